// Round 1
// baseline (1032.715 us; speedup 1.0000x reference)
//
#include <hip/hip_runtime.h>
#include <math.h>

#define HD 128      // hidden dim (= F_IN)
#define ED 16       // edge feat dim
#define NG 64       // num graphs
#define NC 10       // num classes

// ---------------- CSR build ----------------
__global__ void k_hist(const int* __restrict__ dst, int* __restrict__ deg, int E){
  int e = blockIdx.x*blockDim.x + threadIdx.x;
  if(e<E) atomicAdd(&deg[dst[e]], 1);
}

__global__ __launch_bounds__(1024) void k_scan(const int* __restrict__ deg, int* __restrict__ offs, int N){
  __shared__ int part[1024];
  int tid = threadIdx.x;
  int chunk = (N + 1023) >> 10;
  int base = tid*chunk;
  int s = 0;
  for(int i=0;i<chunk;i++){ int idx=base+i; if(idx<N) s += deg[idx]; }
  part[tid]=s; __syncthreads();
  for(int off=1; off<1024; off<<=1){
    int v = (tid>=off) ? part[tid-off] : 0;
    __syncthreads();
    part[tid] += v;
    __syncthreads();
  }
  int run = (tid==0)?0:part[tid-1];
  for(int i=0;i<chunk;i++){ int idx=base+i; if(idx<N){ offs[idx]=run; run += deg[idx]; } }
  if(tid==1023) offs[N]=part[1023];
}

__global__ void k_scatter(const int* __restrict__ dst, int* __restrict__ cursor,
                          int* __restrict__ ce, int E){
  int e = blockIdx.x*blockDim.x + threadIdx.x;
  if(e<E){ int p = atomicAdd(&cursor[dst[e]], 1); ce[p] = e; }
}

// ---------------- GEMM: Z[M x 128] = A[M x 128] @ W[128 x 128], fp32 ----------------
__global__ __launch_bounds__(256) void k_gemm(const float* __restrict__ A,
                                              const float* __restrict__ W,
                                              float* __restrict__ Z, int M){
  __shared__ float As[64][33];   // padded: scalar writes, broadcast reads
  __shared__ float Ws[32][HD];
  int tid = threadIdx.x;
  int block_row = blockIdx.x*64;
  int cg = tid & 31; int c0 = cg*4;     // 4 output cols
  int rg = tid >> 5; int r0 = rg*8;     // 8 output rows
  float acc[8][4];
  #pragma unroll
  for(int i=0;i<8;i++){ acc[i][0]=0.f; acc[i][1]=0.f; acc[i][2]=0.f; acc[i][3]=0.f; }

  int lr = tid>>3, lk=(tid&7)*4;        // A tile load mapping
  for(int kt=0; kt<HD; kt+=32){
    #pragma unroll
    for(int rr=0; rr<64; rr+=32){
      int grow = block_row + rr + lr;
      float4 v = make_float4(0.f,0.f,0.f,0.f);
      if(grow < M) v = *(const float4*)&A[(size_t)grow*HD + kt + lk];
      As[rr+lr][lk+0]=v.x; As[rr+lr][lk+1]=v.y; As[rr+lr][lk+2]=v.z; As[rr+lr][lk+3]=v.w;
    }
    #pragma unroll
    for(int kk=0; kk<32; kk+=8){
      int gk = kt + kk + (tid>>5);
      float4 w = *(const float4*)&W[(size_t)gk*HD + (tid&31)*4];
      *(float4*)&Ws[kk+(tid>>5)][(tid&31)*4] = w;
    }
    __syncthreads();
    #pragma unroll
    for(int kk=0; kk<32; kk++){
      float4 w = *(float4*)&Ws[kk][c0];
      float a[8];
      #pragma unroll
      for(int i=0;i<8;i++) a[i] = As[r0+i][kk];
      #pragma unroll
      for(int i=0;i<8;i++){
        acc[i][0] = fmaf(a[i], w.x, acc[i][0]);
        acc[i][1] = fmaf(a[i], w.y, acc[i][1]);
        acc[i][2] = fmaf(a[i], w.z, acc[i][2]);
        acc[i][3] = fmaf(a[i], w.w, acc[i][3]);
      }
    }
    __syncthreads();
  }
  #pragma unroll
  for(int i=0;i<8;i++){
    int grow = block_row + r0 + i;
    if(grow < M){
      float4 v = make_float4(acc[i][0],acc[i][1],acc[i][2],acc[i][3]);
      *(float4*)&Z[(size_t)grow*HD + c0] = v;
    }
  }
}

// ---------------- per-node attention dots: ps[v]=z[v].a_src, pd[v]=z[v].a_dst ----------------
__global__ __launch_bounds__(256) void k_pdots(const float* __restrict__ z,
                                               const float* __restrict__ a,
                                               float* __restrict__ ps, float* __restrict__ pd, int N){
  int wid = blockIdx.x*4 + (threadIdx.x>>6);
  int lane = threadIdx.x & 63;
  if(wid >= N) return;
  float z0 = z[(size_t)wid*HD + lane];
  float z1 = z[(size_t)wid*HD + 64 + lane];
  float s = z0*a[lane]       + z1*a[64+lane];
  float d = z0*a[HD+lane]    + z1*a[HD+64+lane];
  #pragma unroll
  for(int o=32;o;o>>=1){ s += __shfl_xor(s,o); d += __shfl_xor(d,o); }
  if(lane==0){ ps[wid]=s; pd[wid]=d; }
}

// ---------------- edge logits (leaky 0.2) ----------------
__global__ void k_edge(const float* __restrict__ ef, const float* __restrict__ ae,
                       const int* __restrict__ src, const int* __restrict__ dst,
                       const float* __restrict__ ps, const float* __restrict__ pd,
                       float* __restrict__ logits, int E){
  int e = blockIdx.x*blockDim.x + threadIdx.x;
  if(e>=E) return;
  const float* f = &ef[(size_t)e*ED];
  float q = 0.f;
  #pragma unroll
  for(int i=0;i<ED;i++) q = fmaf(f[i], ae[i], q);
  float l = ps[src[e]] + pd[dst[e]] + q;
  logits[e] = (l >= 0.f) ? l : 0.2f*l;
}

// ---------------- per-dst softmax + aggregate + relu + fused att ----------------
__global__ __launch_bounds__(256) void k_agg(const float* __restrict__ z,
                                             const float* __restrict__ logits,
                                             const int* __restrict__ offs,
                                             const int* __restrict__ ce,
                                             const int* __restrict__ src,
                                             float* __restrict__ hout,
                                             float* __restrict__ att,
                                             const float* __restrict__ watt,
                                             const float* __restrict__ batt, int N){
  int wid = blockIdx.x*4 + (threadIdx.x>>6);
  int lane = threadIdx.x & 63;
  if(wid >= N) return;
  int d0 = offs[wid], d1 = offs[wid+1];
  // pass 1: max
  float m = -INFINITY;
  for(int j=d0+lane; j<d1; j+=64) m = fmaxf(m, logits[ce[j]]);
  #pragma unroll
  for(int o=32;o;o>>=1) m = fmaxf(m, __shfl_xor(m,o));
  // pass 2: sum of exp
  float s = 0.f;
  for(int j=d0+lane; j<d1; j+=64) s += __expf(logits[ce[j]] - m);
  #pragma unroll
  for(int o=32;o;o>>=1) s += __shfl_xor(s,o);
  float inv = (d1 > d0) ? 1.0f/s : 0.0f;
  // pass 3: weighted gather
  float acc0 = 0.f, acc1 = 0.f;
  for(int j=d0; j<d1; j++){
    int e = ce[j];                       // wave-uniform broadcast
    float w = __expf(logits[e] - m) * inv;
    int u = src[e];
    acc0 = fmaf(w, z[(size_t)u*HD + lane],      acc0);
    acc1 = fmaf(w, z[(size_t)u*HD + 64 + lane], acc1);
  }
  acc0 = fmaxf(acc0, 0.f); acc1 = fmaxf(acc1, 0.f);   // relu
  hout[(size_t)wid*HD + lane]      = acc0;
  hout[(size_t)wid*HD + 64 + lane] = acc1;
  // fused readout attention scalar
  float t = acc0*watt[lane] + acc1*watt[64+lane];
  #pragma unroll
  for(int o=32;o;o>>=1) t += __shfl_xor(t,o);
  t += batt[0];
  float lr = (t >= 0.f) ? t : 0.01f*t;
  if(lane==0) att[wid] = __expf(lr);
}

// ---------------- readout: hg[g] += sum att[v]*h[v]; cnt[g] = group size ----------------
#define RCH 8
__global__ __launch_bounds__(128) void k_readout(const float* __restrict__ h,
                                                 const float* __restrict__ att,
                                                 const int* __restrict__ gid,
                                                 float* __restrict__ hg,
                                                 float* __restrict__ cnt, int N){
  int g = blockIdx.x / RCH;
  int chunk = blockIdx.x % RCH;
  int f = threadIdx.x;
  // lower_bound(g), lower_bound(g+1) over sorted gid
  int lo=0, hi=N;
  while(lo<hi){ int mid=(lo+hi)>>1; if(gid[mid] < g) lo=mid+1; else hi=mid; }
  int start = lo;
  lo = start; hi = N;
  while(lo<hi){ int mid=(lo+hi)>>1; if(gid[mid] < g+1) lo=mid+1; else hi=mid; }
  int end = lo;
  int len = end - start;
  int c0 = start + (int)(((long long)len * chunk) / RCH);
  int c1 = start + (int)(((long long)len * (chunk+1)) / RCH);
  float acc = 0.f;
  for(int v=c0; v<c1; v++) acc = fmaf(att[v], h[(size_t)v*HD + f], acc);
  atomicAdd(&hg[g*HD + f], acc);
  if(chunk==0 && f==0) cnt[g] = (float)len;
}

// ---------------- final: y = [hg1/c, hg2/c, hg3/c] @ Wc + bc; log_softmax ----------------
__global__ __launch_bounds__(256) void k_final(const float* __restrict__ hg,
                                               const float* __restrict__ cnt,
                                               const float* __restrict__ Wc,
                                               const float* __restrict__ bc,
                                               float* __restrict__ out){
  __shared__ float y[NG][NC];
  int tid = threadIdx.x;
  for(int idx=tid; idx<NG*NC; idx+=256){
    int g = idx / NC, c = idx % NC;
    float invc = 1.f / fmaxf(cnt[g], 1.f);
    float s = bc[c];
    #pragma unroll
    for(int part=0; part<3; part++){
      const float* row = &hg[part*NG*HD + g*HD];
      for(int f=0; f<HD; f++) s = fmaf(row[f]*invc, Wc[(part*HD+f)*NC + c], s);
    }
    y[g][c] = s;
  }
  __syncthreads();
  if(tid < NG){
    float mx = -INFINITY;
    #pragma unroll
    for(int c=0;c<NC;c++) mx = fmaxf(mx, y[tid][c]);
    float s = 0.f;
    #pragma unroll
    for(int c=0;c<NC;c++) s += __expf(y[tid][c] - mx);
    float ls = logf(s);
    #pragma unroll
    for(int c=0;c<NC;c++) out[tid*NC + c] = y[tid][c] - mx - ls;
  }
}

// ---------------- host ----------------
extern "C" void kernel_launch(void* const* d_in, const int* in_sizes, int n_in,
                              void* d_out, int out_size, void* d_ws, size_t ws_size,
                              hipStream_t stream) {
  const float* x     = (const float*)d_in[0];
  const float* efeat = (const float*)d_in[1];
  const int*   src   = (const int*)d_in[2];
  const int*   dst   = (const int*)d_in[3];
  const int*   gid   = (const int*)d_in[4];
  const float* W1    = (const float*)d_in[5];
  const float* a1    = (const float*)d_in[6];
  const float* W2    = (const float*)d_in[7];
  const float* a2    = (const float*)d_in[8];
  const float* W3    = (const float*)d_in[9];
  const float* a3    = (const float*)d_in[10];
  const float* watt  = (const float*)d_in[11];
  const float* batt  = (const float*)d_in[12];
  const float* Wc    = (const float*)d_in[13];
  const float* bc    = (const float*)d_in[14];
  float* out = (float*)d_out;

  int N = in_sizes[4];
  int E = in_sizes[2];

  // workspace bump allocator (256B aligned)
  char* p = (char*)d_ws;
  auto alloc = [&](size_t bytes)->void*{
    void* r = (void*)p;
    p += (bytes + 255) & ~(size_t)255;
    return r;
  };
  float* B1     = (float*)alloc((size_t)N*HD*4);   // z buffer
  float* B2     = (float*)alloc((size_t)N*HD*4);   // h buffer
  float* ps     = (float*)alloc((size_t)N*4);
  float* pd     = (float*)alloc((size_t)N*4);
  float* logits = (float*)alloc((size_t)E*4);
  float* att    = (float*)alloc((size_t)N*4);
  int*   deg    = (int*)  alloc((size_t)N*4);
  int*   offs   = (int*)  alloc((size_t)(N+1)*4);
  int*   cursor = (int*)  alloc((size_t)N*4);
  int*   ce     = (int*)  alloc((size_t)E*4);
  float* hg     = (float*)alloc((size_t)3*NG*HD*4);
  float* cnt    = (float*)alloc((size_t)NG*4);
  (void)ws_size; (void)n_in; (void)out_size;

  int ethreads = 256;
  int eblocks = (E + ethreads - 1) / ethreads;
  int nwblocks = (N + 3) / 4;            // wave-per-node kernels, 4 waves/block
  int gemmblocks = (N + 63) / 64;

  // --- CSR build (src/dst fixed across layers) ---
  hipMemsetAsync(deg, 0, (size_t)N*4, stream);
  hipMemsetAsync(hg, 0, (size_t)3*NG*HD*4, stream);
  k_hist<<<eblocks, ethreads, 0, stream>>>(dst, deg, E);
  k_scan<<<1, 1024, 0, stream>>>(deg, offs, N);
  hipMemcpyAsync(cursor, offs, (size_t)N*4, hipMemcpyDeviceToDevice, stream);
  k_scatter<<<eblocks, ethreads, 0, stream>>>(dst, cursor, ce, E);

  const float* Ws[3] = {W1, W2, W3};
  const float* as[3] = {a1, a2, a3};
  for(int layer=0; layer<3; layer++){
    const float* hin = (layer==0) ? x : B2;
    k_gemm<<<gemmblocks, 256, 0, stream>>>(hin, Ws[layer], B1, N);
    k_pdots<<<nwblocks, 256, 0, stream>>>(B1, as[layer], ps, pd, N);
    k_edge<<<eblocks, ethreads, 0, stream>>>(efeat, as[layer] + 2*HD, src, dst, ps, pd, logits, E);
    k_agg<<<nwblocks, 256, 0, stream>>>(B1, logits, offs, ce, src, B2, att, watt, batt, N);
    k_readout<<<NG*RCH, HD, 0, stream>>>(B2, att, gid, hg + layer*NG*HD, cnt, N);
  }
  k_final<<<1, 256, 0, stream>>>(hg, cnt, Wc, bc, out);
}

// Round 2
// 886.177 us; speedup vs baseline: 1.1654x; 1.1654x over previous
//
#include <hip/hip_runtime.h>
#include <math.h>

#define HD 128      // hidden dim (= F_IN)
#define ED 16       // edge feat dim
#define NG 64       // num graphs
#define NC 10       // num classes

__device__ __forceinline__ unsigned short f2b(float x){
  unsigned u = __float_as_uint(x);
  unsigned r = (u + 0x7fffu + ((u >> 16) & 1u)) >> 16;
  return (unsigned short)r;
}

// ---------------- CSR build ----------------
__global__ void k_hist(const int* __restrict__ dst, int* __restrict__ deg, int E){
  int e = blockIdx.x*blockDim.x + threadIdx.x;
  if(e<E) atomicAdd(&deg[dst[e]], 1);
}

__global__ __launch_bounds__(1024) void k_scan(const int* __restrict__ deg, int* __restrict__ offs, int N){
  __shared__ int part[1024];
  int tid = threadIdx.x;
  int chunk = (N + 1023) >> 10;
  int base = tid*chunk;
  int s = 0;
  for(int i=0;i<chunk;i++){ int idx=base+i; if(idx<N) s += deg[idx]; }
  part[tid]=s; __syncthreads();
  for(int off=1; off<1024; off<<=1){
    int v = (tid>=off) ? part[tid-off] : 0;
    __syncthreads();
    part[tid] += v;
    __syncthreads();
  }
  int run = (tid==0)?0:part[tid-1];
  for(int i=0;i<chunk;i++){ int idx=base+i; if(idx<N){ offs[idx]=run; run += deg[idx]; } }
  if(tid==1023) offs[N]=part[1023];
}

__global__ void k_scatter(const int* __restrict__ dst, int* __restrict__ cursor,
                          int* __restrict__ ce, int E){
  int e = blockIdx.x*blockDim.x + threadIdx.x;
  if(e<E){ int p = atomicAdd(&cursor[dst[e]], 1); ce[p] = e; }
}

// ---------------- GEMM: Z[M x 128] = A[M x 128] @ W[128 x 128], fp32 (+bf16 copy) ----------------
__global__ __launch_bounds__(256) void k_gemm(const float* __restrict__ A,
                                              const float* __restrict__ W,
                                              float* __restrict__ Z,
                                              unsigned short* __restrict__ Zb, int M){
  __shared__ float As[64][33];   // padded: scalar writes, broadcast reads
  __shared__ float Ws[32][HD];
  int tid = threadIdx.x;
  int block_row = blockIdx.x*64;
  int cg = tid & 31; int c0 = cg*4;     // 4 output cols
  int rg = tid >> 5; int r0 = rg*8;     // 8 output rows
  float acc[8][4];
  #pragma unroll
  for(int i=0;i<8;i++){ acc[i][0]=0.f; acc[i][1]=0.f; acc[i][2]=0.f; acc[i][3]=0.f; }

  int lr = tid>>3, lk=(tid&7)*4;        // A tile load mapping
  for(int kt=0; kt<HD; kt+=32){
    #pragma unroll
    for(int rr=0; rr<64; rr+=32){
      int grow = block_row + rr + lr;
      float4 v = make_float4(0.f,0.f,0.f,0.f);
      if(grow < M) v = *(const float4*)&A[(size_t)grow*HD + kt + lk];
      As[rr+lr][lk+0]=v.x; As[rr+lr][lk+1]=v.y; As[rr+lr][lk+2]=v.z; As[rr+lr][lk+3]=v.w;
    }
    #pragma unroll
    for(int kk=0; kk<32; kk+=8){
      int gk = kt + kk + (tid>>5);
      float4 w = *(const float4*)&W[(size_t)gk*HD + (tid&31)*4];
      *(float4*)&Ws[kk+(tid>>5)][(tid&31)*4] = w;
    }
    __syncthreads();
    #pragma unroll
    for(int kk=0; kk<32; kk++){
      float4 w = *(float4*)&Ws[kk][c0];
      float a[8];
      #pragma unroll
      for(int i=0;i<8;i++) a[i] = As[r0+i][kk];
      #pragma unroll
      for(int i=0;i<8;i++){
        acc[i][0] = fmaf(a[i], w.x, acc[i][0]);
        acc[i][1] = fmaf(a[i], w.y, acc[i][1]);
        acc[i][2] = fmaf(a[i], w.z, acc[i][2]);
        acc[i][3] = fmaf(a[i], w.w, acc[i][3]);
      }
    }
    __syncthreads();
  }
  #pragma unroll
  for(int i=0;i<8;i++){
    int grow = block_row + r0 + i;
    if(grow < M){
      float4 v = make_float4(acc[i][0],acc[i][1],acc[i][2],acc[i][3]);
      *(float4*)&Z[(size_t)grow*HD + c0] = v;
      ushort4 b;
      b.x = f2b(acc[i][0]); b.y = f2b(acc[i][1]);
      b.z = f2b(acc[i][2]); b.w = f2b(acc[i][3]);
      *(ushort4*)&Zb[(size_t)grow*HD + c0] = b;
    }
  }
}

// ---------------- per-node attention dots: ps[v]=z[v].a_src, pd[v]=z[v].a_dst ----------------
__global__ __launch_bounds__(256) void k_pdots(const float* __restrict__ z,
                                               const float* __restrict__ a,
                                               float* __restrict__ ps, float* __restrict__ pd, int N){
  int wid = blockIdx.x*4 + (threadIdx.x>>6);
  int lane = threadIdx.x & 63;
  if(wid >= N) return;
  float z0 = z[(size_t)wid*HD + lane];
  float z1 = z[(size_t)wid*HD + 64 + lane];
  float s = z0*a[lane]       + z1*a[64+lane];
  float d = z0*a[HD+lane]    + z1*a[HD+64+lane];
  #pragma unroll
  for(int o=32;o;o>>=1){ s += __shfl_xor(s,o); d += __shfl_xor(d,o); }
  if(lane==0){ ps[wid]=s; pd[wid]=d; }
}

// ---------------- edge logits (leaky 0.2) ----------------
__global__ void k_edge(const float* __restrict__ ef, const float* __restrict__ ae,
                       const int* __restrict__ src, const int* __restrict__ dst,
                       const float* __restrict__ ps, const float* __restrict__ pd,
                       float* __restrict__ logits, int E){
  int e = blockIdx.x*blockDim.x + threadIdx.x;
  if(e>=E) return;
  const float* f = &ef[(size_t)e*ED];
  float q = 0.f;
  #pragma unroll
  for(int i=0;i<ED;i++) q = fmaf(f[i], ae[i], q);
  float l = ps[src[e]] + pd[dst[e]] + q;
  logits[e] = (l >= 0.f) ? l : 0.2f*l;
}

// ---------------- per-dst softmax + aggregate (bf16 gather) + relu + fused att ----------------
__global__ __launch_bounds__(256) void k_agg(const unsigned* __restrict__ zb,   // N x 64 uints (2 bf16 each)
                                             const float* __restrict__ logits,
                                             const int* __restrict__ offs,
                                             const int* __restrict__ ce,
                                             const int* __restrict__ src,
                                             float* __restrict__ hout,
                                             float* __restrict__ att,
                                             const float* __restrict__ watt,
                                             const float* __restrict__ batt, int N){
  int wid = blockIdx.x*4 + (threadIdx.x>>6);
  int lane = threadIdx.x & 63;
  if(wid >= N) return;
  int d0 = offs[wid], d1 = offs[wid+1];
  // pass 1: max
  float m = -INFINITY;
  for(int j=d0+lane; j<d1; j+=64) m = fmaxf(m, logits[ce[j]]);
  #pragma unroll
  for(int o=32;o;o>>=1) m = fmaxf(m, __shfl_xor(m,o));
  // pass 2: sum of exp
  float s = 0.f;
  for(int j=d0+lane; j<d1; j+=64) s += __expf(logits[ce[j]] - m);
  #pragma unroll
  for(int o=32;o;o>>=1) s += __shfl_xor(s,o);
  float inv = (d1 > d0) ? 1.0f/s : 0.0f;
  // pass 3: weighted gather, unrolled x2 for MLP. lane covers cols 2*lane, 2*lane+1.
  float acc0 = 0.f, acc1 = 0.f;
  int j = d0;
  for(; j+1 < d1; j += 2){
    int e0 = ce[j], e1 = ce[j+1];
    float l0 = logits[e0], l1 = logits[e1];
    int u0 = src[e0], u1 = src[e1];
    unsigned p0 = zb[(size_t)u0*64 + lane];
    unsigned p1 = zb[(size_t)u1*64 + lane];
    float w0 = __expf(l0 - m) * inv;
    float w1 = __expf(l1 - m) * inv;
    acc0 = fmaf(w0, __uint_as_float(p0 << 16),        acc0);
    acc1 = fmaf(w0, __uint_as_float(p0 & 0xffff0000u), acc1);
    acc0 = fmaf(w1, __uint_as_float(p1 << 16),        acc0);
    acc1 = fmaf(w1, __uint_as_float(p1 & 0xffff0000u), acc1);
  }
  if(j < d1){
    int e0 = ce[j];
    float w0 = __expf(logits[e0] - m) * inv;
    unsigned p0 = zb[(size_t)src[e0]*64 + lane];
    acc0 = fmaf(w0, __uint_as_float(p0 << 16),        acc0);
    acc1 = fmaf(w0, __uint_as_float(p0 & 0xffff0000u), acc1);
  }
  acc0 = fmaxf(acc0, 0.f); acc1 = fmaxf(acc1, 0.f);   // relu
  float2 hv = make_float2(acc0, acc1);
  *(float2*)&hout[(size_t)wid*HD + 2*lane] = hv;
  // fused readout attention scalar
  float2 wv = *(const float2*)&watt[2*lane];
  float t = acc0*wv.x + acc1*wv.y;
  #pragma unroll
  for(int o=32;o;o>>=1) t += __shfl_xor(t,o);
  t += batt[0];
  float lr = (t >= 0.f) ? t : 0.01f*t;
  if(lane==0) att[wid] = __expf(lr);
}

// ---------------- readout: hg[g] += sum att[v]*h[v]; cnt[g] = group size ----------------
#define RCH 8
__global__ __launch_bounds__(128) void k_readout(const float* __restrict__ h,
                                                 const float* __restrict__ att,
                                                 const int* __restrict__ gid,
                                                 float* __restrict__ hg,
                                                 float* __restrict__ cnt, int N){
  int g = blockIdx.x / RCH;
  int chunk = blockIdx.x % RCH;
  int f = threadIdx.x;
  int lo=0, hi=N;
  while(lo<hi){ int mid=(lo+hi)>>1; if(gid[mid] < g) lo=mid+1; else hi=mid; }
  int start = lo;
  lo = start; hi = N;
  while(lo<hi){ int mid=(lo+hi)>>1; if(gid[mid] < g+1) lo=mid+1; else hi=mid; }
  int end = lo;
  int len = end - start;
  int c0 = start + (int)(((long long)len * chunk) / RCH);
  int c1 = start + (int)(((long long)len * (chunk+1)) / RCH);
  float acc = 0.f;
  for(int v=c0; v<c1; v++) acc = fmaf(att[v], h[(size_t)v*HD + f], acc);
  atomicAdd(&hg[g*HD + f], acc);
  if(chunk==0 && f==0) cnt[g] = (float)len;
}

// ---------------- final: y = [hg1/c, hg2/c, hg3/c] @ Wc + bc; log_softmax ----------------
__global__ __launch_bounds__(256) void k_final(const float* __restrict__ hg,
                                               const float* __restrict__ cnt,
                                               const float* __restrict__ Wc,
                                               const float* __restrict__ bc,
                                               float* __restrict__ out){
  __shared__ float y[NG][NC];
  int tid = threadIdx.x;
  for(int idx=tid; idx<NG*NC; idx+=256){
    int g = idx / NC, c = idx % NC;
    float invc = 1.f / fmaxf(cnt[g], 1.f);
    float s = bc[c];
    #pragma unroll
    for(int part=0; part<3; part++){
      const float* row = &hg[part*NG*HD + g*HD];
      for(int f=0; f<HD; f++) s = fmaf(row[f]*invc, Wc[(part*HD+f)*NC + c], s);
    }
    y[g][c] = s;
  }
  __syncthreads();
  if(tid < NG){
    float mx = -INFINITY;
    #pragma unroll
    for(int c=0;c<NC;c++) mx = fmaxf(mx, y[tid][c]);
    float s = 0.f;
    #pragma unroll
    for(int c=0;c<NC;c++) s += __expf(y[tid][c] - mx);
    float ls = logf(s);
    #pragma unroll
    for(int c=0;c<NC;c++) out[tid*NC + c] = y[tid][c] - mx - ls;
  }
}

// ---------------- host ----------------
extern "C" void kernel_launch(void* const* d_in, const int* in_sizes, int n_in,
                              void* d_out, int out_size, void* d_ws, size_t ws_size,
                              hipStream_t stream) {
  const float* x     = (const float*)d_in[0];
  const float* efeat = (const float*)d_in[1];
  const int*   src   = (const int*)d_in[2];
  const int*   dst   = (const int*)d_in[3];
  const int*   gid   = (const int*)d_in[4];
  const float* W1    = (const float*)d_in[5];
  const float* a1    = (const float*)d_in[6];
  const float* W2    = (const float*)d_in[7];
  const float* a2    = (const float*)d_in[8];
  const float* W3    = (const float*)d_in[9];
  const float* a3    = (const float*)d_in[10];
  const float* watt  = (const float*)d_in[11];
  const float* batt  = (const float*)d_in[12];
  const float* Wc    = (const float*)d_in[13];
  const float* bc    = (const float*)d_in[14];
  float* out = (float*)d_out;

  int N = in_sizes[4];
  int E = in_sizes[2];

  char* p = (char*)d_ws;
  auto alloc = [&](size_t bytes)->void*{
    void* r = (void*)p;
    p += (bytes + 255) & ~(size_t)255;
    return r;
  };
  float* B1     = (float*)alloc((size_t)N*HD*4);   // z buffer (fp32)
  float* B2     = (float*)alloc((size_t)N*HD*4);   // h buffer (fp32)
  unsigned short* Zb = (unsigned short*)alloc((size_t)N*HD*2);  // z in bf16
  float* ps     = (float*)alloc((size_t)N*4);
  float* pd     = (float*)alloc((size_t)N*4);
  float* logits = (float*)alloc((size_t)E*4);
  float* att    = (float*)alloc((size_t)N*4);
  int*   deg    = (int*)  alloc((size_t)N*4);
  int*   offs   = (int*)  alloc((size_t)(N+1)*4);
  int*   cursor = (int*)  alloc((size_t)N*4);
  int*   ce     = (int*)  alloc((size_t)E*4);
  float* hg     = (float*)alloc((size_t)3*NG*HD*4);
  float* cnt    = (float*)alloc((size_t)NG*4);
  (void)ws_size; (void)n_in; (void)out_size;

  int ethreads = 256;
  int eblocks = (E + ethreads - 1) / ethreads;
  int nwblocks = (N + 3) / 4;
  int gemmblocks = (N + 63) / 64;

  hipMemsetAsync(deg, 0, (size_t)N*4, stream);
  hipMemsetAsync(hg, 0, (size_t)3*NG*HD*4, stream);
  k_hist<<<eblocks, ethreads, 0, stream>>>(dst, deg, E);
  k_scan<<<1, 1024, 0, stream>>>(deg, offs, N);
  hipMemcpyAsync(cursor, offs, (size_t)N*4, hipMemcpyDeviceToDevice, stream);
  k_scatter<<<eblocks, ethreads, 0, stream>>>(dst, cursor, ce, E);

  const float* Ws[3] = {W1, W2, W3};
  const float* as[3] = {a1, a2, a3};
  for(int layer=0; layer<3; layer++){
    const float* hin = (layer==0) ? x : B2;
    k_gemm<<<gemmblocks, 256, 0, stream>>>(hin, Ws[layer], B1, Zb, N);
    k_pdots<<<nwblocks, 256, 0, stream>>>(B1, as[layer], ps, pd, N);
    k_edge<<<eblocks, ethreads, 0, stream>>>(efeat, as[layer] + 2*HD, src, dst, ps, pd, logits, E);
    k_agg<<<nwblocks, 256, 0, stream>>>((const unsigned*)Zb, logits, offs, ce, src, B2, att, watt, batt, N);
    k_readout<<<NG*RCH, HD, 0, stream>>>(B2, att, gid, hg + layer*NG*HD, cnt, N);
  }
  k_final<<<1, 256, 0, stream>>>(hg, cnt, Wc, bc, out);
}

// Round 3
// 732.560 us; speedup vs baseline: 1.4097x; 1.2097x over previous
//
#include <hip/hip_runtime.h>
#include <math.h>

#define HD 128      // hidden dim (= F_IN)
#define ED 16       // edge feat dim
#define NG 64       // num graphs
#define NC 10       // num classes

__device__ __forceinline__ unsigned short f2b(float x){
  unsigned u = __float_as_uint(x);
  unsigned r = (u + 0x7fffu + ((u >> 16) & 1u)) >> 16;
  return (unsigned short)r;
}

// ---------------- CSR build ----------------
__global__ void k_hist(const int* __restrict__ dst, int* __restrict__ deg, int E){
  int e = blockIdx.x*blockDim.x + threadIdx.x;
  if(e<E) atomicAdd(&deg[dst[e]], 1);
}

// block-partial sums: block b sums deg[b*256 .. b*256+255]
__global__ __launch_bounds__(64) void k_bsum(const int* __restrict__ deg, int* __restrict__ bsum, int N){
  int b = blockIdx.x, t = threadIdx.x;
  int i = b*256 + t*4;
  int s = 0;
  if(i+3 < N){ int4 v = *(const int4*)&deg[i]; s = v.x+v.y+v.z+v.w; }
  else { for(int k=0;k<4;k++) if(i+k<N) s += deg[i+k]; }
  #pragma unroll
  for(int o=32;o;o>>=1) s += __shfl_xor(s,o);
  if(t==0) bsum[b] = s;
}

// single-block scan of block partials (nb <= 1024)
__global__ __launch_bounds__(1024) void k_bscan(const int* __restrict__ bsum, int* __restrict__ bbase,
                                                int* __restrict__ offs, int N, int nb){
  __shared__ int sh[1024];
  int t = threadIdx.x;
  int v = (t < nb) ? bsum[t] : 0;
  sh[t] = v; __syncthreads();
  for(int o=1;o<1024;o<<=1){ int u = (t>=o)?sh[t-o]:0; __syncthreads(); sh[t]+=u; __syncthreads(); }
  if(t < nb) bbase[t] = sh[t] - v;           // exclusive
  if(t == 1023) offs[N] = sh[1023];          // total
}

// per-block local scan + base → offs, cursor
__global__ __launch_bounds__(256) void k_bprop(const int* __restrict__ deg, const int* __restrict__ bbase,
                                               int* __restrict__ offs, int* __restrict__ cursor, int N){
  __shared__ int sh[256];
  int b = blockIdx.x, t = threadIdx.x;
  int i = b*256 + t;
  int v = (i<N) ? deg[i] : 0;
  sh[t] = v; __syncthreads();
  for(int o=1;o<256;o<<=1){ int u = (t>=o)?sh[t-o]:0; __syncthreads(); sh[t]+=u; __syncthreads(); }
  if(i<N){ int o_ = bbase[b] + sh[t] - v; offs[i] = o_; cursor[i] = o_; }
}

__global__ void k_scatter(const int* __restrict__ src, const int* __restrict__ dst,
                          int* __restrict__ cursor, int* __restrict__ pos,
                          int* __restrict__ src_csr, int* __restrict__ dst_csr, int E){
  int e = blockIdx.x*blockDim.x + threadIdx.x;
  if(e<E){
    int d = dst[e];
    int p = atomicAdd(&cursor[d], 1);
    pos[e] = p;
    src_csr[p] = src[e];
    dst_csr[p] = d;
  }
}

// one pass over e_feat computing q for all 3 layers, stored CSR-ordered
__global__ void k_eq(const float* __restrict__ ef,
                     const float* __restrict__ a1e, const float* __restrict__ a2e, const float* __restrict__ a3e,
                     const int* __restrict__ pos, float* __restrict__ q, int E){
  int e = blockIdx.x*blockDim.x + threadIdx.x;
  if(e>=E) return;
  const float* f = &ef[(size_t)e*ED];
  float q1=0.f, q2=0.f, q3=0.f;
  #pragma unroll
  for(int i=0;i<ED;i++){
    float fv = f[i];
    q1 = fmaf(fv, a1e[i], q1);
    q2 = fmaf(fv, a2e[i], q2);
    q3 = fmaf(fv, a3e[i], q3);
  }
  int j = pos[e];
  q[j] = q1; q[(size_t)E + j] = q2; q[2*(size_t)E + j] = q3;
}

// ---------------- GEMM: Z[M x 128] = A[M x 128] @ W[128 x 128], fp32 (+bf16 copy) ----------------
__global__ __launch_bounds__(256) void k_gemm(const float* __restrict__ A,
                                              const float* __restrict__ W,
                                              float* __restrict__ Z,
                                              unsigned short* __restrict__ Zb, int M){
  __shared__ float As[64][33];
  __shared__ float Ws[32][HD];
  int tid = threadIdx.x;
  int block_row = blockIdx.x*64;
  int cg = tid & 31; int c0 = cg*4;
  int rg = tid >> 5; int r0 = rg*8;
  float acc[8][4];
  #pragma unroll
  for(int i=0;i<8;i++){ acc[i][0]=0.f; acc[i][1]=0.f; acc[i][2]=0.f; acc[i][3]=0.f; }

  int lr = tid>>3, lk=(tid&7)*4;
  for(int kt=0; kt<HD; kt+=32){
    #pragma unroll
    for(int rr=0; rr<64; rr+=32){
      int grow = block_row + rr + lr;
      float4 v = make_float4(0.f,0.f,0.f,0.f);
      if(grow < M) v = *(const float4*)&A[(size_t)grow*HD + kt + lk];
      As[rr+lr][lk+0]=v.x; As[rr+lr][lk+1]=v.y; As[rr+lr][lk+2]=v.z; As[rr+lr][lk+3]=v.w;
    }
    #pragma unroll
    for(int kk=0; kk<32; kk+=8){
      int gk = kt + kk + (tid>>5);
      float4 w = *(const float4*)&W[(size_t)gk*HD + (tid&31)*4];
      *(float4*)&Ws[kk+(tid>>5)][(tid&31)*4] = w;
    }
    __syncthreads();
    #pragma unroll
    for(int kk=0; kk<32; kk++){
      float4 w = *(float4*)&Ws[kk][c0];
      float a[8];
      #pragma unroll
      for(int i=0;i<8;i++) a[i] = As[r0+i][kk];
      #pragma unroll
      for(int i=0;i<8;i++){
        acc[i][0] = fmaf(a[i], w.x, acc[i][0]);
        acc[i][1] = fmaf(a[i], w.y, acc[i][1]);
        acc[i][2] = fmaf(a[i], w.z, acc[i][2]);
        acc[i][3] = fmaf(a[i], w.w, acc[i][3]);
      }
    }
    __syncthreads();
  }
  #pragma unroll
  for(int i=0;i<8;i++){
    int grow = block_row + r0 + i;
    if(grow < M){
      float4 v = make_float4(acc[i][0],acc[i][1],acc[i][2],acc[i][3]);
      *(float4*)&Z[(size_t)grow*HD + c0] = v;
      ushort4 b;
      b.x = f2b(acc[i][0]); b.y = f2b(acc[i][1]);
      b.z = f2b(acc[i][2]); b.w = f2b(acc[i][3]);
      *(ushort4*)&Zb[(size_t)grow*HD + c0] = b;
    }
  }
}

// ---------------- per-node attention dots ----------------
__global__ __launch_bounds__(256) void k_pdots(const float* __restrict__ z,
                                               const float* __restrict__ a,
                                               float* __restrict__ ps, float* __restrict__ pd, int N){
  int wid = blockIdx.x*4 + (threadIdx.x>>6);
  int lane = threadIdx.x & 63;
  if(wid >= N) return;
  float z0 = z[(size_t)wid*HD + lane];
  float z1 = z[(size_t)wid*HD + 64 + lane];
  float s = z0*a[lane]       + z1*a[64+lane];
  float d = z0*a[HD+lane]    + z1*a[HD+64+lane];
  #pragma unroll
  for(int o=32;o;o>>=1){ s += __shfl_xor(s,o); d += __shfl_xor(d,o); }
  if(lane==0){ ps[wid]=s; pd[wid]=d; }
}

// ---------------- edge logits in CSR order (leaky 0.2) ----------------
__global__ void k_logits(const float* __restrict__ ps, const float* __restrict__ pd,
                         const int* __restrict__ src_csr, const int* __restrict__ dst_csr,
                         const float* __restrict__ q, float* __restrict__ lg, int E){
  int j = blockIdx.x*blockDim.x + threadIdx.x;
  if(j>=E) return;
  float l = ps[src_csr[j]] + pd[dst_csr[j]] + q[j];
  lg[j] = (l >= 0.f) ? l : 0.2f*l;
}

// ---------------- per-dst softmax + aggregate (bf16 gather) + relu + fused att ----------------
__global__ __launch_bounds__(256) void k_agg(const unsigned* __restrict__ zb,   // N x 64 uints (2 bf16)
                                             const float* __restrict__ lg,     // CSR-ordered logits
                                             const int* __restrict__ offs,
                                             const int* __restrict__ src_csr,
                                             float* __restrict__ hout,
                                             float* __restrict__ att,
                                             const float* __restrict__ watt,
                                             const float* __restrict__ batt, int N){
  int wid = blockIdx.x*4 + (threadIdx.x>>6);
  int lane = threadIdx.x & 63;
  if(wid >= N) return;
  int d0 = offs[wid], d1 = offs[wid+1];
  // pass 1: max (contiguous)
  float m = -INFINITY;
  for(int j=d0+lane; j<d1; j+=64) m = fmaxf(m, lg[j]);
  #pragma unroll
  for(int o=32;o;o>>=1) m = fmaxf(m, __shfl_xor(m,o));
  // pass 2: sum of exp (contiguous)
  float s = 0.f;
  for(int j=d0+lane; j<d1; j+=64) s += __expf(lg[j] - m);
  #pragma unroll
  for(int o=32;o;o>>=1) s += __shfl_xor(s,o);
  float inv = (d1 > d0) ? 1.0f/s : 0.0f;
  // pass 3: weighted gather, unrolled x2
  float acc0 = 0.f, acc1 = 0.f;
  int j = d0;
  for(; j+1 < d1; j += 2){
    float l0 = lg[j], l1 = lg[j+1];
    int u0 = src_csr[j], u1 = src_csr[j+1];
    unsigned p0 = zb[(size_t)u0*64 + lane];
    unsigned p1 = zb[(size_t)u1*64 + lane];
    float w0 = __expf(l0 - m) * inv;
    float w1 = __expf(l1 - m) * inv;
    acc0 = fmaf(w0, __uint_as_float(p0 << 16),         acc0);
    acc1 = fmaf(w0, __uint_as_float(p0 & 0xffff0000u), acc1);
    acc0 = fmaf(w1, __uint_as_float(p1 << 16),         acc0);
    acc1 = fmaf(w1, __uint_as_float(p1 & 0xffff0000u), acc1);
  }
  if(j < d1){
    float w0 = __expf(lg[j] - m) * inv;
    unsigned p0 = zb[(size_t)src_csr[j]*64 + lane];
    acc0 = fmaf(w0, __uint_as_float(p0 << 16),         acc0);
    acc1 = fmaf(w0, __uint_as_float(p0 & 0xffff0000u), acc1);
  }
  acc0 = fmaxf(acc0, 0.f); acc1 = fmaxf(acc1, 0.f);
  *(float2*)&hout[(size_t)wid*HD + 2*lane] = make_float2(acc0, acc1);
  float2 wv = *(const float2*)&watt[2*lane];
  float t = acc0*wv.x + acc1*wv.y;
  #pragma unroll
  for(int o=32;o;o>>=1) t += __shfl_xor(t,o);
  t += batt[0];
  float lr = (t >= 0.f) ? t : 0.01f*t;
  if(lane==0) att[wid] = __expf(lr);
}

// ---------------- readout ----------------
#define RCH 8
__global__ __launch_bounds__(128) void k_readout(const float* __restrict__ h,
                                                 const float* __restrict__ att,
                                                 const int* __restrict__ gid,
                                                 float* __restrict__ hg,
                                                 float* __restrict__ cnt, int N){
  int g = blockIdx.x / RCH;
  int chunk = blockIdx.x % RCH;
  int f = threadIdx.x;
  int lo=0, hi=N;
  while(lo<hi){ int mid=(lo+hi)>>1; if(gid[mid] < g) lo=mid+1; else hi=mid; }
  int start = lo;
  lo = start; hi = N;
  while(lo<hi){ int mid=(lo+hi)>>1; if(gid[mid] < g+1) lo=mid+1; else hi=mid; }
  int end = lo;
  int len = end - start;
  int c0 = start + (int)(((long long)len * chunk) / RCH);
  int c1 = start + (int)(((long long)len * (chunk+1)) / RCH);
  float acc = 0.f;
  for(int v=c0; v<c1; v++) acc = fmaf(att[v], h[(size_t)v*HD + f], acc);
  atomicAdd(&hg[g*HD + f], acc);
  if(chunk==0 && f==0) cnt[g] = (float)len;
}

// ---------------- final ----------------
__global__ __launch_bounds__(256) void k_final(const float* __restrict__ hg,
                                               const float* __restrict__ cnt,
                                               const float* __restrict__ Wc,
                                               const float* __restrict__ bc,
                                               float* __restrict__ out){
  __shared__ float y[NG][NC];
  int tid = threadIdx.x;
  for(int idx=tid; idx<NG*NC; idx+=256){
    int g = idx / NC, c = idx % NC;
    float invc = 1.f / fmaxf(cnt[g], 1.f);
    float s = bc[c];
    #pragma unroll
    for(int part=0; part<3; part++){
      const float* row = &hg[part*NG*HD + g*HD];
      for(int f=0; f<HD; f++) s = fmaf(row[f]*invc, Wc[(part*HD+f)*NC + c], s);
    }
    y[g][c] = s;
  }
  __syncthreads();
  if(tid < NG){
    float mx = -INFINITY;
    #pragma unroll
    for(int c=0;c<NC;c++) mx = fmaxf(mx, y[tid][c]);
    float s = 0.f;
    #pragma unroll
    for(int c=0;c<NC;c++) s += __expf(y[tid][c] - mx);
    float ls = logf(s);
    #pragma unroll
    for(int c=0;c<NC;c++) out[tid*NC + c] = y[tid][c] - mx - ls;
  }
}

// ---------------- host ----------------
extern "C" void kernel_launch(void* const* d_in, const int* in_sizes, int n_in,
                              void* d_out, int out_size, void* d_ws, size_t ws_size,
                              hipStream_t stream) {
  const float* x     = (const float*)d_in[0];
  const float* efeat = (const float*)d_in[1];
  const int*   src   = (const int*)d_in[2];
  const int*   dst   = (const int*)d_in[3];
  const int*   gid   = (const int*)d_in[4];
  const float* W1    = (const float*)d_in[5];
  const float* a1    = (const float*)d_in[6];
  const float* W2    = (const float*)d_in[7];
  const float* a2    = (const float*)d_in[8];
  const float* W3    = (const float*)d_in[9];
  const float* a3    = (const float*)d_in[10];
  const float* watt  = (const float*)d_in[11];
  const float* batt  = (const float*)d_in[12];
  const float* Wc    = (const float*)d_in[13];
  const float* bc    = (const float*)d_in[14];
  float* out = (float*)d_out;

  int N = in_sizes[4];
  int E = in_sizes[2];

  char* p = (char*)d_ws;
  auto alloc = [&](size_t bytes)->void*{
    void* r = (void*)p;
    p += (bytes + 255) & ~(size_t)255;
    return r;
  };
  float* B1      = (float*)alloc((size_t)N*HD*4);   // z fp32
  float* B2      = (float*)alloc((size_t)N*HD*4);   // h fp32
  unsigned short* Zb = (unsigned short*)alloc((size_t)N*HD*2);  // z bf16
  float* ps      = (float*)alloc((size_t)N*4);
  float* pd      = (float*)alloc((size_t)N*4);
  float* att     = (float*)alloc((size_t)N*4);
  int*   deg     = (int*)  alloc((size_t)N*4);
  int*   offs    = (int*)  alloc((size_t)(N+1)*4);
  int*   cursor  = (int*)  alloc((size_t)N*4);
  int*   pos     = (int*)  alloc((size_t)E*4);
  int*   src_csr = (int*)  alloc((size_t)E*4);
  int*   dst_csr = (int*)  alloc((size_t)E*4);
  float* qcsr    = (float*)alloc((size_t)3*E*4);
  float* lgits   = (float*)alloc((size_t)E*4);
  int*   bsum    = (int*)  alloc((size_t)1024*4);
  int*   bbase   = (int*)  alloc((size_t)1024*4);
  float* hg      = (float*)alloc((size_t)3*NG*HD*4);
  float* cnt     = (float*)alloc((size_t)NG*4);
  (void)ws_size; (void)n_in; (void)out_size;

  int ethreads = 256;
  int eblocks = (E + ethreads - 1) / ethreads;
  int nwblocks = (N + 3) / 4;
  int gemmblocks = (N + 63) / 64;
  int nb = (N + 255) / 256;               // 196 for N=50000 (<= 1024)

  hipMemsetAsync(deg, 0, (size_t)N*4, stream);
  hipMemsetAsync(hg, 0, (size_t)3*NG*HD*4, stream);
  k_hist<<<eblocks, ethreads, 0, stream>>>(dst, deg, E);
  k_bsum<<<nb, 64, 0, stream>>>(deg, bsum, N);
  k_bscan<<<1, 1024, 0, stream>>>(bsum, bbase, offs, N, nb);
  k_bprop<<<nb, 256, 0, stream>>>(deg, bbase, offs, cursor, N);
  k_scatter<<<eblocks, ethreads, 0, stream>>>(src, dst, cursor, pos, src_csr, dst_csr, E);
  k_eq<<<eblocks, ethreads, 0, stream>>>(efeat, a1+2*HD, a2+2*HD, a3+2*HD, pos, qcsr, E);

  const float* Ws[3] = {W1, W2, W3};
  const float* as[3] = {a1, a2, a3};
  for(int layer=0; layer<3; layer++){
    const float* hin = (layer==0) ? x : B2;
    k_gemm<<<gemmblocks, 256, 0, stream>>>(hin, Ws[layer], B1, Zb, N);
    k_pdots<<<nwblocks, 256, 0, stream>>>(B1, as[layer], ps, pd, N);
    k_logits<<<eblocks, ethreads, 0, stream>>>(ps, pd, src_csr, dst_csr, qcsr + (size_t)layer*E, lgits, E);
    k_agg<<<nwblocks, 256, 0, stream>>>((const unsigned*)Zb, lgits, offs, src_csr, B2, att, watt, batt, N);
    k_readout<<<NG*RCH, HD, 0, stream>>>(B2, att, gid, hg + layer*NG*HD, cnt, N);
  }
  k_final<<<1, 256, 0, stream>>>(hg, cnt, Wc, bc, out);
}